// Round 1
// 317.001 us; speedup vs baseline: 1.0500x; 1.0500x over previous
//
#include <hip/hip_runtime.h>

// CorrelationPyramid on MI355X — round 5: deep-pipelined proj gather +
// fully-fused pooling/normalization chain.
//
// Pipeline (6 dispatches):
//   1) proj_mfma   : 1x1 conv C=128 -> 64 via mfma_f32_16x16x32_f16, fused
//                    level-0 L2-normalize + f16 cast in the epilogue.
//                    Input gather now loads all 64 strided fp32 values into a
//                    register array BEFORE converting (63-deep vmcnt pipeline;
//                    the old 8-deep batching exposed ~64x900cy of HBM latency
//                    per block and held proj at 27% of HBM peak).
//   2) pool_all    : ONE kernel replaces pool x3 + norm16. Reads un-normalized
//                    fp32 L0 NHWC once; each 16-lane group owns one L2 (40x40)
//                    output pixel's 64 channels; computes the 4 L1 pixels +
//                    L2 pixel + (via shfl_xor 16/32 across the wave's 2x2 L2
//                    group) the L3 pixel; L2-normalizes each and writes f16
//                    directly. No q1/q2/q3 fp32 round-trips.
//   3) corr_mfma<R> x4: unchanged — one WAVE per (bn, h, w-tile), no LDS, no
//                    barriers; bn = blockIdx%8 pins each value image to one
//                    XCD's L2.

typedef _Float16 f16;
typedef _Float16 f16x4 __attribute__((ext_vector_type(4)));
typedef _Float16 f16x8 __attribute__((ext_vector_type(8)));
typedef float f32x4 __attribute__((ext_vector_type(4)));

#define EPSN 1e-12f

// ---------------- projection via MFMA, fused level-0 normalize ----------------
#define XS 136

__global__ __launch_bounds__(256, 3) void proj_mfma(
    const float* __restrict__ xq, const float* __restrict__ xv,
    const float* __restrict__ wt, const float* __restrict__ bias,
    float* __restrict__ outf, f16* __restrict__ outh, int P) {
  __shared__ f16 xs[128 * XS];   // 34,816 B
  __shared__ f16 ws[64 * XS];    // 17,408 B

  int bid = blockIdx.x;
  int img = bid / 200;           // 10 images: 0,1 = query; 2..9 = values
  int p0 = (bid - img * 200) * 128;
  const float* xsrc = (img < 2) ? (xq + (size_t)img * 128 * P)
                                : (xv + (size_t)(img - 2) * 128 * P);

  int tid = threadIdx.x;
  int lane = tid & 63;
  int wv = tid >> 6;
  int cl = lane & 15;
  int quad = lane >> 4;

  for (int it = tid; it < 64 * 16; it += 256) {
    int o = it >> 4, g = it & 15;
    float4 w0 = *(const float4*)(wt + o * 128 + g * 8);
    float4 w1 = *(const float4*)(wt + o * 128 + g * 8 + 4);
    f16x8 h;
    h[0] = (f16)w0.x; h[1] = (f16)w0.y; h[2] = (f16)w0.z; h[3] = (f16)w0.w;
    h[4] = (f16)w1.x; h[5] = (f16)w1.y; h[6] = (f16)w1.z; h[7] = (f16)w1.w;
    *(f16x8*)(ws + o * XS + g * 8) = h;
  }

  {
    int pxs = tid & 127;
    int c0 = (tid >> 7) * 64;
    const float* xp = xsrc + (size_t)c0 * P + p0 + pxs;
    // Phase 1: issue ALL 64 strided loads (independent, constant-indexed
    // register array -> compiler keeps them in flight, no per-batch waits).
    float v[64];
#pragma unroll
    for (int k = 0; k < 64; ++k) v[k] = xp[(size_t)k * P];
    // Phase 2: convert + LDS write (drains vmcnt progressively).
#pragma unroll
    for (int i = 0; i < 8; ++i) {
      f16x8 h;
#pragma unroll
      for (int k = 0; k < 8; ++k) h[k] = (f16)v[8 * i + k];
      *(f16x8*)(xs + pxs * XS + c0 + 8 * i) = h;
    }
  }
  __syncthreads();

  f32x4 acc[2][4];
#pragma unroll
  for (int a = 0; a < 2; ++a)
#pragma unroll
    for (int m = 0; m < 4; ++m) acc[a][m] = (f32x4)0.f;

#pragma unroll
  for (int kc = 0; kc < 4; ++kc) {
    f16x8 bfr[2], afr[4];
#pragma unroll
    for (int pt = 0; pt < 2; ++pt) {
      int px = (2 * wv + pt) * 16 + cl;
      bfr[pt] = *(const f16x8*)(xs + px * XS + kc * 32 + quad * 8);
    }
#pragma unroll
    for (int mt = 0; mt < 4; ++mt) {
      int o = mt * 16 + cl;
      afr[mt] = *(const f16x8*)(ws + o * XS + kc * 32 + quad * 8);
    }
#pragma unroll
    for (int pt = 0; pt < 2; ++pt)
#pragma unroll
      for (int mt = 0; mt < 4; ++mt)
        acc[pt][mt] = __builtin_amdgcn_mfma_f32_16x16x32_f16(afr[mt], bfr[pt], acc[pt][mt], 0, 0, 0);
  }

  float4 bi[4];
#pragma unroll
  for (int mt = 0; mt < 4; ++mt) bi[mt] = *(const float4*)(bias + mt * 16 + quad * 4);

#pragma unroll
  for (int pt = 0; pt < 2; ++pt) {
    int px = p0 + (2 * wv + pt) * 16 + cl;
    float ss = 0.f;
#pragma unroll
    for (int mt = 0; mt < 4; ++mt) {
      acc[pt][mt][0] += bi[mt].x;
      acc[pt][mt][1] += bi[mt].y;
      acc[pt][mt][2] += bi[mt].z;
      acc[pt][mt][3] += bi[mt].w;
#pragma unroll
      for (int r = 0; r < 4; ++r) ss = fmaf(acc[pt][mt][r], acc[pt][mt][r], ss);
    }
    ss += __shfl_xor(ss, 16, 64);
    ss += __shfl_xor(ss, 32, 64);
    float s = 1.0f / fmaxf(sqrtf(ss), EPSN);
    size_t base = ((size_t)img * P + px) * 64;
#pragma unroll
    for (int mt = 0; mt < 4; ++mt) {
      *(float4*)(outf + base + mt * 16 + quad * 4) =
          make_float4(acc[pt][mt][0], acc[pt][mt][1], acc[pt][mt][2], acc[pt][mt][3]);
      f16x4 hn;
      hn[0] = (f16)(acc[pt][mt][0] * s);
      hn[1] = (f16)(acc[pt][mt][1] * s);
      hn[2] = (f16)(acc[pt][mt][2] * s);
      hn[3] = (f16)(acc[pt][mt][3] * s);
      *(f16x4*)(outh + base + mt * 16 + quad * 4) = hn;
    }
  }
}

// ---------------- fused 4x4 pool + per-level L2-normalize -> f16 -------------
// One thread = 4 channels (c4) of one L2 (40x40) output pixel.
// 16-lane group (c4=0..15) = all 64 channels of that pixel.
// 4 groups of a wave (g = (tid>>4)&3) = a 2x2 block of L2 pixels -> one L3
// pixel via shfl_xor(16/32).
// Emits: qh1 (80x80 f16 norm), qh2 (40x40), qh3 (20x20). No fp32 intermediates.
__global__ __launch_bounds__(256) void pool_all(
    const float* __restrict__ q0, f16* __restrict__ qh1,
    f16* __restrict__ qh2, f16* __restrict__ qh3) {
  int gid = blockIdx.x * 256 + threadIdx.x;   // total = 10*20*20*64 = 256000
  int c4 = gid & 15;
  int g = (gid >> 4) & 3;
  int idx = gid >> 6;            // [0, 4000)
  int w3 = idx % 20;
  int t = idx / 20;
  int h3 = t % 20;
  int img = t / 20;
  int h2 = 2 * h3 + (g >> 1);
  int w2 = 2 * w3 + (g & 1);

  const float4* in4 = (const float4*)q0;
  size_t base = ((size_t)(img * 160 + 4 * h2) * 160 + 4 * w2) * 16 + c4;
  float4 a[16];
#pragma unroll
  for (int i = 0; i < 4; ++i)
#pragma unroll
    for (int j = 0; j < 4; ++j)
      a[i * 4 + j] = in4[base + (size_t)i * 160 * 16 + j * 16];

  // level-1 pixels (2x2 of them) + level-2 pixel
  float4 v1[4];
  float4 q2v = make_float4(0.f, 0.f, 0.f, 0.f);
#pragma unroll
  for (int i1 = 0; i1 < 2; ++i1)
#pragma unroll
    for (int j1 = 0; j1 < 2; ++j1) {
      float4 s00 = a[(2 * i1) * 4 + 2 * j1];
      float4 s01 = a[(2 * i1) * 4 + 2 * j1 + 1];
      float4 s10 = a[(2 * i1 + 1) * 4 + 2 * j1];
      float4 s11 = a[(2 * i1 + 1) * 4 + 2 * j1 + 1];
      float4 r;
      r.x = 0.25f * (s00.x + s01.x + s10.x + s11.x);
      r.y = 0.25f * (s00.y + s01.y + s10.y + s11.y);
      r.z = 0.25f * (s00.z + s01.z + s10.z + s11.z);
      r.w = 0.25f * (s00.w + s01.w + s10.w + s11.w);
      v1[i1 * 2 + j1] = r;
      q2v.x += r.x; q2v.y += r.y; q2v.z += r.z; q2v.w += r.w;
    }
  q2v.x *= 0.25f; q2v.y *= 0.25f; q2v.z *= 0.25f; q2v.w *= 0.25f;

  // level-1: normalize + write f16
#pragma unroll
  for (int i1 = 0; i1 < 2; ++i1)
#pragma unroll
    for (int j1 = 0; j1 < 2; ++j1) {
      float4 r = v1[i1 * 2 + j1];
      float ss = fmaf(r.x, r.x, fmaf(r.y, r.y, fmaf(r.z, r.z, r.w * r.w)));
      ss += __shfl_xor(ss, 1, 64);
      ss += __shfl_xor(ss, 2, 64);
      ss += __shfl_xor(ss, 4, 64);
      ss += __shfl_xor(ss, 8, 64);
      float s = 1.0f / fmaxf(sqrtf(ss), EPSN);
      int y1 = 2 * h2 + i1, x1 = 2 * w2 + j1;
      f16x4 h;
      h[0] = (f16)(r.x * s); h[1] = (f16)(r.y * s);
      h[2] = (f16)(r.z * s); h[3] = (f16)(r.w * s);
      *(f16x4*)(qh1 + ((size_t)(img * 80 + y1) * 80 + x1) * 64 + c4 * 4) = h;
    }

  // level-2: normalize + write f16
  {
    float ss = fmaf(q2v.x, q2v.x, fmaf(q2v.y, q2v.y, fmaf(q2v.z, q2v.z, q2v.w * q2v.w)));
    ss += __shfl_xor(ss, 1, 64);
    ss += __shfl_xor(ss, 2, 64);
    ss += __shfl_xor(ss, 4, 64);
    ss += __shfl_xor(ss, 8, 64);
    float s = 1.0f / fmaxf(sqrtf(ss), EPSN);
    f16x4 h;
    h[0] = (f16)(q2v.x * s); h[1] = (f16)(q2v.y * s);
    h[2] = (f16)(q2v.z * s); h[3] = (f16)(q2v.w * s);
    *(f16x4*)(qh2 + ((size_t)(img * 40 + h2) * 40 + w2) * 64 + c4 * 4) = h;
  }

  // level-3: cross-group (2x2 L2 pixels) average, normalize, write from g==0
  {
    float4 q3v;
    q3v.x = q2v.x + __shfl_xor(q2v.x, 16, 64);
    q3v.y = q2v.y + __shfl_xor(q2v.y, 16, 64);
    q3v.z = q2v.z + __shfl_xor(q2v.z, 16, 64);
    q3v.w = q2v.w + __shfl_xor(q2v.w, 16, 64);
    q3v.x += __shfl_xor(q3v.x, 32, 64);
    q3v.y += __shfl_xor(q3v.y, 32, 64);
    q3v.z += __shfl_xor(q3v.z, 32, 64);
    q3v.w += __shfl_xor(q3v.w, 32, 64);
    q3v.x *= 0.25f; q3v.y *= 0.25f; q3v.z *= 0.25f; q3v.w *= 0.25f;
    float ss = fmaf(q3v.x, q3v.x, fmaf(q3v.y, q3v.y, fmaf(q3v.z, q3v.z, q3v.w * q3v.w)));
    ss += __shfl_xor(ss, 1, 64);
    ss += __shfl_xor(ss, 2, 64);
    ss += __shfl_xor(ss, 4, 64);
    ss += __shfl_xor(ss, 8, 64);
    float s = 1.0f / fmaxf(sqrtf(ss), EPSN);
    if (g == 0) {
      f16x4 h;
      h[0] = (f16)(q3v.x * s); h[1] = (f16)(q3v.y * s);
      h[2] = (f16)(q3v.z * s); h[3] = (f16)(q3v.w * s);
      *(f16x4*)(qh3 + ((size_t)(img * 20 + h3) * 20 + w3) * 64 + c4 * 4) = h;
    }
  }
}

// ---------------- correlation: one wave per (bn, h, w-tile) ----------------
// No LDS, no barriers. Band tiles: T0 cols (w0-R+cl) mod W -> D rows 0-7
// (quads 0,1), dxi = r - cl + 2R;  T1 cols (w0+R+cl) mod W -> rows 8-15
// (quads 2,3), dxi = r - cl.  Exact partition for R <= 4. Each (w,dy,dx)
// written exactly once; partial w-tiles (W%16) masked on store.
// C/D layout: col = lane&15, row = (lane>>4)*4 + reg.
template <int R>
__global__ __launch_bounds__(256, 8) void corr_mfma(
    const f16* __restrict__ qh, const f16* __restrict__ vh,
    float* __restrict__ out, int H, int W, int T) {
  constexpr int D = 2 * R + 1, DD = D * D;
  int bn = blockIdx.x & 7;               // 8 bn values -> 8 XCDs (heuristic)
  int wv = threadIdx.x >> 6;
  int widx = (blockIdx.x >> 3) * 4 + wv; // [0, H*T)
  int h = widx / T;
  int wt = widx - h * T;
  int lane = threadIdx.x & 63;
  int cl = lane & 15, quad = lane >> 4;
  int b = bn >> 2;
  int w0 = wt * 16;

  // A fragments (q row), loaded once
  int ap = w0 + cl; if (ap >= W) ap = W - 1;   // clamp partial tile
  const f16* qp = qh + ((size_t)(b * H + h) * W + ap) * 64 + quad * 8;
  f16x8 a0 = *(const f16x8*)qp;
  f16x8 a1 = *(const f16x8*)(qp + 32);

  // B pixel offsets (roll wraparound), fixed across dy
  int c0 = w0 - R + cl; if (c0 < 0) c0 += W; if (c0 >= W) c0 -= W;
  int c1 = w0 + R + cl; if (c1 >= W) c1 -= W;
  int b0off = c0 * 64 + quad * 8;
  int b1off = c1 * 64 + quad * 8;

  // store offsets: out[pix*DD + dyi*D + dxi], pix = (bn*H+h)*W + w
  int rbase = quad * 4;
  int base_dxi = rbase - cl + ((quad < 2) ? 2 * R : 0);
  int wr0 = w0 + rbase;
  int off0 = ((bn * H + h) * W + wr0) * DD + base_dxi;

  for (int dyi = 0; dyi < D; ++dyi) {
    int h2 = h - dyi + R; if (h2 < 0) h2 += H; else if (h2 >= H) h2 -= H;
    const f16* vrow = vh + ((size_t)(bn * H + h2) * W) * 64;
    f16x8 b0a = *(const f16x8*)(vrow + b0off);
    f16x8 b0b = *(const f16x8*)(vrow + b0off + 32);
    f16x8 b1a = *(const f16x8*)(vrow + b1off);
    f16x8 b1b = *(const f16x8*)(vrow + b1off + 32);
    f32x4 A0 = __builtin_amdgcn_mfma_f32_16x16x32_f16(a0, b0a, (f32x4)0.f, 0, 0, 0);
    A0 = __builtin_amdgcn_mfma_f32_16x16x32_f16(a1, b0b, A0, 0, 0, 0);
    f32x4 A1 = __builtin_amdgcn_mfma_f32_16x16x32_f16(a0, b1a, (f32x4)0.f, 0, 0, 0);
    A1 = __builtin_amdgcn_mfma_f32_16x16x32_f16(a1, b1b, A1, 0, 0, 0);
#pragma unroll
    for (int rr = 0; rr < 4; ++rr) {
      int dxi = base_dxi + rr;
      float val = (quad < 2) ? A0[rr] : A1[rr];
      if ((unsigned)dxi <= (unsigned)(2 * R) && (wr0 + rr) < W)
        out[off0 + dyi * D + rr * (DD + 1)] = val;
    }
  }
}

extern "C" void kernel_launch(void* const* d_in, const int* in_sizes, int n_in,
                              void* d_out, int out_size, void* d_ws, size_t ws_size,
                              hipStream_t stream) {
  const float* query  = (const float*)d_in[0];   // [2,128,160,160]
  const float* values = (const float*)d_in[1];   // [2,4,128,160,160]
  const float* pw     = (const float*)d_in[2];   // [64,128]
  const float* pb     = (const float*)d_in[3];   // [64]
  float* out = (float*)d_out;
  float* ws  = (float*)d_ws;

  const int B = 2, N = 4;
  const int P0 = 160 * 160;

  // Workspace layout (floats):
  //   [0, 10*P0*64)            q0+v0 un-normalized fp32 NHWC (proj out, pool in)
  //   then level-0 f16 (10 images), then levels 1-3 f16 (10 images each).
  float* q0 = ws;
  f16* q0h = (f16*)(ws + (size_t)10 * P0 * 64);
  f16* v0h = q0h + (size_t)2 * P0 * 64;
  f16* qh1 = q0h + (size_t)10 * P0 * 64;
  f16* vh1 = qh1 + (size_t)2 * (P0 / 4) * 64;
  f16* qh2 = vh1 + (size_t)8 * (P0 / 4) * 64;
  f16* vh2 = qh2 + (size_t)2 * (P0 / 16) * 64;
  f16* qh3 = vh2 + (size_t)8 * (P0 / 16) * 64;
  f16* vh3 = qh3 + (size_t)2 * (P0 / 64) * 64;

  // 1) projection via MFMA, fused level-0 norm+f16
  proj_mfma<<<2000, 256, 0, stream>>>(query, values, pw, pb, q0, q0h, P0);

  // 2) fused pool+norm chain: one dispatch produces levels 1-3 f16
  pool_all<<<1000, 256, 0, stream>>>(q0, qh1, qh2, qh3);

  // 3) correlation (output tuple concatenated flat)
  float* out0 = out;
  float* out1 = out0 + (size_t)B * N * P0 * 81;
  float* out2 = out1 + (size_t)B * N * (P0 / 4) * 25;
  float* out3 = out2 + (size_t)B * N * (P0 / 16) * 9;
  // waves = 8*H*T; blocks = waves/4 (all divisible by 8)
  corr_mfma<4><<<8 * 160 * 10 / 4, 256, 0, stream>>>(q0h, v0h, out0, 160, 160, 10);
  corr_mfma<2><<<8 * 80 * 5 / 4, 256, 0, stream>>>(qh1, vh1, out1, 80, 80, 5);
  corr_mfma<1><<<8 * 40 * 3 / 4, 256, 0, stream>>>(qh2, vh2, out2, 40, 40, 3);
  corr_mfma<1><<<8 * 20 * 2 / 4, 256, 0, stream>>>(qh3, vh3, out3, 20, 20, 2);
}